// Round 1
// baseline (6229.152 us; speedup 1.0000x reference)
//
#include <hip/hip_runtime.h>

#define LDA 68  // padded leading dim for 64-wide LDS tiles (float4-aligned, bank-spread)

// ---------------------------------------------------------------- utilities

__device__ __forceinline__ void stage_tile(const float* __restrict__ g, int base, int nrows,
                                           float* __restrict__ Ash, int t,
                                           const float* __restrict__ sc, const float* __restrict__ sh)
{
#pragma unroll
    for (int i = 0; i < 4; ++i) {
        int idx = i * 256 + t;
        int r = idx >> 4;
        int c = (idx & 15) << 2;
        float4 v = make_float4(0.f, 0.f, 0.f, 0.f);
        int row = base + r;
        if (row < nrows) v = *(const float4*)(g + (size_t)row * 64 + c);
        if (sc) {
            v.x = v.x * sc[c + 0] + sh[c + 0];
            v.y = v.y * sc[c + 1] + sh[c + 1];
            v.z = v.z * sc[c + 2] + sh[c + 2];
            v.w = v.w * sc[c + 3] + sh[c + 3];
        }
        *(float4*)(Ash + r * LDA + c) = v;
    }
}

__device__ __forceinline__ void stage_w(const float* __restrict__ g, int ldg,
                                        float* __restrict__ Wsh, int t)
{
#pragma unroll
    for (int i = 0; i < 4; ++i) {
        int idx = i * 256 + t;
        int k = idx >> 4;
        int f = (idx & 15) << 2;
        *(float4*)(Wsh + k * 64 + f) = *(const float4*)(g + (size_t)k * ldg + f);
    }
}

// 64x64 GEMM tile: 256 threads, each computes 4 nodes x 4 feats.
__device__ __forceinline__ void gemm_tile(const float* __restrict__ Ash, const float* __restrict__ Wsh,
                                          float acc[4][4], int n0, int f0)
{
#pragma unroll
    for (int k0 = 0; k0 < 64; k0 += 4) {
        float a[4][4], w[4][4];
#pragma unroll
        for (int i = 0; i < 4; ++i) {
            float4 t4 = *(const float4*)(Ash + (n0 + i) * LDA + k0);
            a[i][0] = t4.x; a[i][1] = t4.y; a[i][2] = t4.z; a[i][3] = t4.w;
        }
#pragma unroll
        for (int k = 0; k < 4; ++k) {
            float4 t4 = *(const float4*)(Wsh + (k0 + k) * 64 + f0);
            w[k][0] = t4.x; w[k][1] = t4.y; w[k][2] = t4.z; w[k][3] = t4.w;
        }
#pragma unroll
        for (int i = 0; i < 4; ++i)
#pragma unroll
            for (int k = 0; k < 4; ++k)
#pragma unroll
                for (int j = 0; j < 4; ++j)
                    acc[i][j] = fmaf(a[i][k], w[k][j], acc[i][j]);
    }
}

// ---------------------------------------------------------------- CSR build

__global__ void k_count(const int* __restrict__ dst, int* __restrict__ cnt, int E)
{
    int e = blockIdx.x * 256 + threadIdx.x;
    if (e < E) atomicAdd(&cnt[dst[e]], 1);
}

__global__ void k_scan(const int* __restrict__ cnt, int* __restrict__ rowptr, int n)
{
    __shared__ int part[1024];
    int t = threadIdx.x;
    int C = (n + 1023) >> 10;
    int lo = t * C, hi = min(lo + C, n);
    int s = 0;
    for (int i = lo; i < hi; ++i) s += cnt[i];
    part[t] = s;
    __syncthreads();
    for (int off = 1; off < 1024; off <<= 1) {
        int v = (t >= off) ? part[t - off] : 0;
        __syncthreads();
        part[t] += v;
        __syncthreads();
    }
    int pre = (t == 0) ? 0 : part[t - 1];
    for (int i = lo; i < hi; ++i) { rowptr[i] = pre; pre += cnt[i]; }
    if (t == 1023) rowptr[n] = part[1023];
}

__global__ void k_fill(const int* __restrict__ src, const int* __restrict__ dst,
                       const int* __restrict__ rowptr, int* __restrict__ cursor,
                       int* __restrict__ col, int E)
{
    int e = blockIdx.x * 256 + threadIdx.x;
    if (e < E) {
        int d = dst[e];
        int p = atomicAdd(&cursor[d], 1);
        col[rowptr[d] + p] = src[e];
    }
}

// ---------------------------------------------------------------- BN stats / finalize

__global__ void k_xstats(const float* __restrict__ x, float* __restrict__ stats, int N)
{
    __shared__ float rs[256], rq[256];
    int t = threadIdx.x;
    int f = t & 63, rg = t >> 6;
    float s = 0.f, q = 0.f;
    for (int r = blockIdx.x * 4 + rg; r < N; r += gridDim.x * 4) {
        float v = x[(size_t)r * 64 + f];
        s += v; q += v * v;
    }
    rs[rg * 64 + f] = s; rq[rg * 64 + f] = q;
    __syncthreads();
    if (t < 64) {
        float ts = rs[t] + rs[64 + t] + rs[128 + t] + rs[192 + t];
        float tq = rq[t] + rq[64 + t] + rq[128 + t] + rq[192 + t];
        atomicAdd(&stats[t], ts);
        atomicAdd(&stats[64 + t], tq);
    }
}

__global__ void k_finalize(const float* __restrict__ stats, const float* __restrict__ gamma,
                           const float* __restrict__ beta, float* __restrict__ ss, float invN)
{
    int t = threadIdx.x;
    if (t < 64) {
        float mu = stats[t] * invN;
        float var = stats[64 + t] * invN - mu * mu;
        float rs = rsqrtf(var + 1e-5f);
        float sc = gamma[t] * rs;
        ss[t] = sc;
        ss[64 + t] = beta[t] - mu * sc;
    }
}

// ---------------------------------------------------------------- input proj

__global__ void k_proj(const float* __restrict__ x, const float* __restrict__ ss,
                       const float* __restrict__ W, const float* __restrict__ b,
                       float* __restrict__ h, float* __restrict__ res, int N)
{
    __shared__ __align__(16) float Ash[64 * LDA];
    __shared__ __align__(16) float Wsh[64 * 64];
    int t = threadIdx.x;
    int base = blockIdx.x * 64;
    stage_tile(x, base, N, Ash, t, ss, ss + 64);
    stage_w(W, 64, Wsh, t);
    __syncthreads();
    int n0 = (t >> 4) << 2, f0 = (t & 15) << 2;
    float acc[4][4];
    float4 b4 = *(const float4*)(b + f0);
#pragma unroll
    for (int i = 0; i < 4; ++i) { acc[i][0] = b4.x; acc[i][1] = b4.y; acc[i][2] = b4.z; acc[i][3] = b4.w; }
    gemm_tile(Ash, Wsh, acc, n0, f0);
#pragma unroll
    for (int i = 0; i < 4; ++i) {
        int row = base + n0 + i;
        if (row < N) {
            float4 o = make_float4(fmaxf(acc[i][0], 0.f), fmaxf(acc[i][1], 0.f),
                                   fmaxf(acc[i][2], 0.f), fmaxf(acc[i][3], 0.f));
            *(float4*)(h + (size_t)row * 64 + f0) = o;
            *(float4*)(res + (size_t)row * 64 + f0) = o;
        }
    }
}

// ---------------------------------------------------------------- fused GIN conv: agg + 3-layer MLP + BN partial stats

__global__ void k_conv(const float* __restrict__ h, const int* __restrict__ rowptr,
                       const int* __restrict__ col, const float* __restrict__ W3,
                       const float* __restrict__ b3, float* __restrict__ z,
                       float* __restrict__ stats, int N)
{
    __shared__ __align__(16) float Ash[64 * LDA];
    __shared__ __align__(16) float Bsh[64 * LDA];
    __shared__ __align__(16) float Wsh[64 * 64];
    int t = threadIdx.x;
    int lane = t & 63, wave = t >> 6;
    int base = blockIdx.x * 64;

    // phase 1: per-wave node aggregation (wave-uniform edge loop; lane = feature)
#pragma unroll 1
    for (int i = 0; i < 16; ++i) {
        int nl = i * 4 + wave;
        int n = base + nl;
        float a = 0.f;
        if (n < N) {
            a = h[(size_t)n * 64 + lane];
            int e0 = rowptr[n], e1 = rowptr[n + 1];
            int e = e0;
            for (; e + 4 <= e1; e += 4) {
                int s0 = col[e], s1 = col[e + 1], s2 = col[e + 2], s3 = col[e + 3];
                float v0 = h[(size_t)s0 * 64 + lane];
                float v1 = h[(size_t)s1 * 64 + lane];
                float v2 = h[(size_t)s2 * 64 + lane];
                float v3 = h[(size_t)s3 * 64 + lane];
                a += (v0 + v1) + (v2 + v3);
            }
            for (; e < e1; ++e) a += h[(size_t)col[e] * 64 + lane];
        }
        Ash[nl * LDA + lane] = a;
    }
    stage_w(W3, 64, Wsh, t);
    __syncthreads();

    int n0 = (t >> 4) << 2, f0 = (t & 15) << 2;
    float acc[4][4];

    // linear 1 + relu
    {
        float4 b4 = *(const float4*)(b3 + f0);
#pragma unroll
        for (int i = 0; i < 4; ++i) { acc[i][0] = b4.x; acc[i][1] = b4.y; acc[i][2] = b4.z; acc[i][3] = b4.w; }
    }
    gemm_tile(Ash, Wsh, acc, n0, f0);
    __syncthreads();
#pragma unroll
    for (int i = 0; i < 4; ++i) {
        float4 o = make_float4(fmaxf(acc[i][0], 0.f), fmaxf(acc[i][1], 0.f),
                               fmaxf(acc[i][2], 0.f), fmaxf(acc[i][3], 0.f));
        *(float4*)(Bsh + (n0 + i) * LDA + f0) = o;
    }
    stage_w(W3 + 64 * 64, 64, Wsh, t);
    __syncthreads();

    // linear 2 + relu
    {
        float4 b4 = *(const float4*)(b3 + 64 + f0);
#pragma unroll
        for (int i = 0; i < 4; ++i) { acc[i][0] = b4.x; acc[i][1] = b4.y; acc[i][2] = b4.z; acc[i][3] = b4.w; }
    }
    gemm_tile(Bsh, Wsh, acc, n0, f0);
    __syncthreads();
#pragma unroll
    for (int i = 0; i < 4; ++i) {
        float4 o = make_float4(fmaxf(acc[i][0], 0.f), fmaxf(acc[i][1], 0.f),
                               fmaxf(acc[i][2], 0.f), fmaxf(acc[i][3], 0.f));
        *(float4*)(Ash + (n0 + i) * LDA + f0) = o;
    }
    stage_w(W3 + 2 * 64 * 64, 64, Wsh, t);
    __syncthreads();

    // linear 3 (no relu; BN follows)
    {
        float4 b4 = *(const float4*)(b3 + 128 + f0);
#pragma unroll
        for (int i = 0; i < 4; ++i) { acc[i][0] = b4.x; acc[i][1] = b4.y; acc[i][2] = b4.z; acc[i][3] = b4.w; }
    }
    gemm_tile(Ash, Wsh, acc, n0, f0);

    // write z + per-block BN partial stats
    float s[4] = {0.f, 0.f, 0.f, 0.f}, q[4] = {0.f, 0.f, 0.f, 0.f};
#pragma unroll
    for (int i = 0; i < 4; ++i) {
        int row = base + n0 + i;
        if (row < N) {
            *(float4*)(z + (size_t)row * 64 + f0) =
                make_float4(acc[i][0], acc[i][1], acc[i][2], acc[i][3]);
#pragma unroll
            for (int j = 0; j < 4; ++j) { s[j] += acc[i][j]; q[j] += acc[i][j] * acc[i][j]; }
        }
    }
    int ng = t >> 4;
#pragma unroll
    for (int j = 0; j < 4; ++j) {
        Bsh[ng * 64 + f0 + j] = s[j];
        Bsh[1024 + ng * 64 + f0 + j] = q[j];
    }
    __syncthreads();
    if (t < 64) {
        float ts = 0.f, tq = 0.f;
#pragma unroll
        for (int g2 = 0; g2 < 16; ++g2) { ts += Bsh[g2 * 64 + t]; tq += Bsh[1024 + g2 * 64 + t]; }
        atomicAdd(&stats[t], ts);
        atomicAdd(&stats[64 + t], tq);
    }
}

// ---------------------------------------------------------------- BN apply + relu (+ residual)

__global__ void k_bnrelu(const float4* __restrict__ z4, const float* __restrict__ ss,
                         float4* __restrict__ h4, float4* __restrict__ res4,
                         int second, int total4)
{
    int idx = blockIdx.x * 256 + threadIdx.x;
    if (idx >= total4) return;
    int c = (idx & 15) << 2;
    float4 v = z4[idx];
    v.x = fmaxf(v.x * ss[c + 0] + ss[64 + c + 0], 0.f);
    v.y = fmaxf(v.y * ss[c + 1] + ss[64 + c + 1], 0.f);
    v.z = fmaxf(v.z * ss[c + 2] + ss[64 + c + 2], 0.f);
    v.w = fmaxf(v.w * ss[c + 3] + ss[64 + c + 3], 0.f);
    if (second) {
        float4 r = res4[idx];
        v.x += r.x; v.y += r.y; v.z += r.z; v.w += r.w;
        res4[idx] = v;
    }
    h4[idx] = v;
}

// ---------------------------------------------------------------- attention readout

__global__ void k_wks(const float* __restrict__ Wk, const float* __restrict__ seed,
                      float* __restrict__ wks)
{
    int t = threadIdx.x;  // 256
    int i = t >> 2, hh = t & 3;
    float s = 0.f;
#pragma unroll
    for (int d = 0; d < 16; ++d) s += Wk[i * 64 + hh * 16 + d] * seed[hh * 16 + d];
    wks[i * 4 + hh] = s * 0.25f;  // 1/sqrt(16)
}

__global__ void k_vs(const float* __restrict__ h, const float* __restrict__ Wv,
                     const float* __restrict__ wksg, float* __restrict__ v,
                     float* __restrict__ scores, int N)
{
    __shared__ __align__(16) float Ash[64 * LDA];
    __shared__ __align__(16) float Wsh[64 * 64];
    __shared__ float wk[256];
    int t = threadIdx.x;
    int base = blockIdx.x * 64;
    stage_tile(h, base, N, Ash, t, nullptr, nullptr);
    stage_w(Wv, 64, Wsh, t);
    wk[t] = wksg[t];
    __syncthreads();
    int n0 = (t >> 4) << 2, f0 = (t & 15) << 2;
    float acc[4][4] = {};
    gemm_tile(Ash, Wsh, acc, n0, f0);
#pragma unroll
    for (int i = 0; i < 4; ++i) {
        int row = base + n0 + i;
        if (row < N)
            *(float4*)(v + (size_t)row * 64 + f0) =
                make_float4(acc[i][0], acc[i][1], acc[i][2], acc[i][3]);
    }
    // scores = h @ wk_s  (one thread per (node, head))
    int n = t >> 2, hh = t & 3;
    float s = 0.f;
#pragma unroll
    for (int k0 = 0; k0 < 64; k0 += 4) {
        float4 a = *(const float4*)(Ash + n * LDA + k0);
        s += a.x * wk[(k0 + 0) * 4 + hh];
        s += a.y * wk[(k0 + 1) * 4 + hh];
        s += a.z * wk[(k0 + 2) * 4 + hh];
        s += a.w * wk[(k0 + 3) * 4 + hh];
    }
    int row = base + n;
    if (row < N) scores[(size_t)row * 4 + hh] = s;
}

__global__ void k_bounds(const int* __restrict__ batch, int* __restrict__ gs,
                         int* __restrict__ ge, int N)
{
    int i = blockIdx.x * 256 + threadIdx.x;
    if (i < N) {
        int b = batch[i];
        atomicMin(&gs[b], i);
        atomicMax(&ge[b], i + 1);
    }
}

__global__ void k_pool(const float4* __restrict__ scores4, const float* __restrict__ v,
                       const int* __restrict__ gs, const int* __restrict__ ge,
                       float* __restrict__ pooled, int N)
{
    int g = blockIdx.x;
    int s = gs[g], e = ge[g];
    int t = threadIdx.x;
    __shared__ float4 rmax[256];
    __shared__ float racc[256];
    __shared__ float resum[16];
    if (s >= e) {
        if (t < 64) pooled[g * 64 + t] = 0.f;
        return;
    }
    // phase 1: per-head max
    float4 m = make_float4(-1e30f, -1e30f, -1e30f, -1e30f);
    for (int i = s + t; i < e; i += 256) {
        float4 sc = scores4[i];
        m.x = fmaxf(m.x, sc.x); m.y = fmaxf(m.y, sc.y);
        m.z = fmaxf(m.z, sc.z); m.w = fmaxf(m.w, sc.w);
    }
    rmax[t] = m;
    __syncthreads();
    for (int off = 128; off; off >>= 1) {
        if (t < off) {
            float4 a = rmax[t], b = rmax[t + off];
            a.x = fmaxf(a.x, b.x); a.y = fmaxf(a.y, b.y);
            a.z = fmaxf(a.z, b.z); a.w = fmaxf(a.w, b.w);
            rmax[t] = a;
        }
        __syncthreads();
    }
    float4 smax = rmax[0];
    int rg = t >> 6, f = t & 63, hh = f >> 4;
    float mx = (hh == 0) ? smax.x : ((hh == 1) ? smax.y : ((hh == 2) ? smax.z : smax.w));
    // phase 2: sum e and e*v
    float acc = 0.f, es = 0.f;
    for (int i = s + rg; i < e; i += 4) {
        float4 sc = scores4[i];
        float scl = (hh == 0) ? sc.x : ((hh == 1) ? sc.y : ((hh == 2) ? sc.z : sc.w));
        float ev = __expf(scl - mx);
        acc += ev * v[(size_t)i * 64 + f];
        if ((f & 15) == 0) es += ev;
    }
    racc[rg * 64 + f] = acc;
    if ((f & 15) == 0) resum[rg * 4 + hh] = es;
    __syncthreads();
    if (t < 64) {
        float tot = racc[t] + racc[64 + t] + racc[128 + t] + racc[192 + t];
        int h2 = t >> 4;
        float den = resum[h2] + resum[4 + h2] + resum[8 + h2] + resum[12 + h2];
        pooled[g * 64 + t] = tot / den;
    }
}

__global__ void k_embed(const float* __restrict__ pooled, const float* __restrict__ Wo,
                        float* __restrict__ out, int G)
{
    __shared__ __align__(16) float Ash[64 * LDA];
    __shared__ __align__(16) float Wsh[64 * 64];
    int t = threadIdx.x;
    int base = blockIdx.x * 64;
    stage_tile(pooled, base, G, Ash, t, nullptr, nullptr);
    stage_w(Wo, 64, Wsh, t);
    __syncthreads();
    int n0 = (t >> 4) << 2, f0 = (t & 15) << 2;
    float acc[4][4] = {};
    gemm_tile(Ash, Wsh, acc, n0, f0);
#pragma unroll
    for (int i = 0; i < 4; ++i) {
        int row = base + n0 + i;
        if (row < G)
            *(float4*)(out + (size_t)row * 64 + f0) =
                make_float4(acc[i][0], acc[i][1], acc[i][2], acc[i][3]);
    }
}

__global__ void k_logits(const float* __restrict__ embed, const float* __restrict__ W,
                         const float* __restrict__ b, float* __restrict__ out, int G)
{
    __shared__ __align__(16) float Ash[64 * LDA];
    __shared__ __align__(16) float Wsh[64 * 64];
    int t = threadIdx.x;
    int base = blockIdx.x * 64;
    int co = blockIdx.y * 64;
    stage_tile(embed, base, G, Ash, t, nullptr, nullptr);
    // stage 64x64 slice of [64,128] pred_W
#pragma unroll
    for (int i = 0; i < 4; ++i) {
        int idx = i * 256 + t;
        int k = idx >> 4;
        int f = (idx & 15) << 2;
        *(float4*)(Wsh + k * 64 + f) = *(const float4*)(W + (size_t)k * 128 + co + f);
    }
    __syncthreads();
    int n0 = (t >> 4) << 2, f0 = (t & 15) << 2;
    float acc[4][4];
    float4 b4 = *(const float4*)(b + co + f0);
#pragma unroll
    for (int i = 0; i < 4; ++i) { acc[i][0] = b4.x; acc[i][1] = b4.y; acc[i][2] = b4.z; acc[i][3] = b4.w; }
    gemm_tile(Ash, Wsh, acc, n0, f0);
#pragma unroll
    for (int i = 0; i < 4; ++i) {
        int row = base + n0 + i;
        if (row < G)
            *(float4*)(out + (size_t)row * 128 + co + f0) =
                make_float4(acc[i][0], acc[i][1], acc[i][2], acc[i][3]);
    }
}

// ---------------------------------------------------------------- launch

extern "C" void kernel_launch(void* const* d_in, const int* in_sizes, int n_in,
                              void* d_out, int out_size, void* d_ws, size_t ws_size,
                              hipStream_t stream)
{
    const float* x     = (const float*)d_in[0];
    const int*   eidx  = (const int*)d_in[1];
    const int*   batch = (const int*)d_in[2];
    const float* fn_g  = (const float*)d_in[3];
    const float* fn_b  = (const float*)d_in[4];
    const float* pW    = (const float*)d_in[5];
    const float* pb    = (const float*)d_in[6];
    const float* mlpW  = (const float*)d_in[7];
    const float* mlpb  = (const float*)d_in[8];
    const float* ngm   = (const float*)d_in[9];
    const float* nbt   = (const float*)d_in[10];
    const float* seed  = (const float*)d_in[11];
    const float* Wk    = (const float*)d_in[12];
    const float* Wv    = (const float*)d_in[13];
    const float* Wo    = (const float*)d_in[14];
    const float* predW = (const float*)d_in[15];
    const float* predb = (const float*)d_in[16];

    const int N = 100000, E = 1000000, G = 1000;
    const int* srcv = eidx;
    const int* dstv = eidx + E;

    char* w = (char*)d_ws;
    auto alloc = [&](size_t bytes) {
        char* p = w;
        w += (bytes + 255) & ~(size_t)255;
        return p;
    };
    const size_t NPAD = 100032;  // 1563 * 64
    float* h      = (float*)alloc(NPAD * 64 * 4);
    float* res    = (float*)alloc(NPAD * 64 * 4);
    float* z      = (float*)alloc(NPAD * 64 * 4);   // also reused as v
    int*   rowptr = (int*)alloc((size_t)(N + 1) * 4);
    int*   cnt    = (int*)alloc((size_t)N * 4);
    int*   col    = (int*)alloc((size_t)E * 4);
    float* stats  = (float*)alloc(9 * 128 * 4);
    float* ss     = (float*)alloc(9 * 128 * 4);
    float* wks    = (float*)alloc(256 * 4);
    float* scores = (float*)alloc(NPAD * 4 * 4);
    int*   gs     = (int*)alloc((size_t)G * 4);
    int*   ge     = (int*)alloc((size_t)G * 4);
    float* pooled = (float*)alloc((size_t)G * 64 * 4);

    float* emb    = (float*)d_out;            // [G,64]
    float* logits = (float*)d_out + G * 64;   // [G,128]

    const int NB = (N + 63) / 64;  // 1563
    const float invN = 1.f / (float)N;

    // CSR build
    hipMemsetAsync(cnt, 0, (size_t)N * 4, stream);
    hipMemsetAsync(stats, 0, 9 * 128 * 4, stream);
    k_count<<<(E + 255) / 256, 256, 0, stream>>>(dstv, cnt, E);
    k_scan<<<1, 1024, 0, stream>>>(cnt, rowptr, N);
    hipMemsetAsync(cnt, 0, (size_t)N * 4, stream);
    k_fill<<<(E + 255) / 256, 256, 0, stream>>>(srcv, dstv, rowptr, cnt, col, E);

    // feature BN + projection
    k_xstats<<<512, 256, 0, stream>>>(x, stats, N);
    k_finalize<<<1, 64, 0, stream>>>(stats, fn_g, fn_b, ss, invN);
    k_proj<<<NB, 256, 0, stream>>>(x, ss, pW, pb, h, res, N);

    // 4 MPNN blocks x 2 GIN convs
    for (int m = 0; m < 4; ++m)
        for (int c = 0; c < 2; ++c) {
            int sidx = 1 + m * 2 + c;
            k_conv<<<NB, 256, 0, stream>>>(h, rowptr, col,
                                           mlpW + (size_t)m * 3 * 64 * 64,
                                           mlpb + (size_t)m * 3 * 64,
                                           z, stats + sidx * 128, N);
            k_finalize<<<1, 64, 0, stream>>>(stats + sidx * 128, ngm + m * 64, nbt + m * 64,
                                             ss + sidx * 128, invN);
            k_bnrelu<<<(N * 16 + 255) / 256, 256, 0, stream>>>(
                (const float4*)z, ss + sidx * 128, (float4*)h, (float4*)res, (c == 1) ? 1 : 0, N * 16);
        }

    // attention readout
    k_wks<<<1, 256, 0, stream>>>(Wk, seed, wks);
    k_vs<<<NB, 256, 0, stream>>>(h, Wv, wks, z, scores, N);
    hipMemsetAsync(gs, 0x7f, (size_t)G * 4, stream);
    hipMemsetAsync(ge, 0, (size_t)G * 4, stream);
    k_bounds<<<(N + 255) / 256, 256, 0, stream>>>(batch, gs, ge, N);
    k_pool<<<G, 256, 0, stream>>>((const float4*)scores, z, gs, ge, pooled, N);
    k_embed<<<(G + 63) / 64, 256, 0, stream>>>(pooled, Wo, emb, G);
    dim3 lg((G + 63) / 64, 2);
    k_logits<<<lg, 256, 0, stream>>>(emb, predW, predb, logits, G);
}

// Round 2
// 5219.303 us; speedup vs baseline: 1.1935x; 1.1935x over previous
//
#include <hip/hip_runtime.h>

#define LDA 68  // padded leading dim for 64-wide LDS tiles (float4-aligned, bank-spread)

// ---------------------------------------------------------------- utilities

__device__ __forceinline__ void stage_tile(const float* __restrict__ g, int base, int nrows,
                                           float* __restrict__ Ash, int t,
                                           const float* __restrict__ sc, const float* __restrict__ sh)
{
#pragma unroll
    for (int i = 0; i < 4; ++i) {
        int idx = i * 256 + t;
        int r = idx >> 4;
        int c = (idx & 15) << 2;
        float4 v = make_float4(0.f, 0.f, 0.f, 0.f);
        int row = base + r;
        if (row < nrows) v = *(const float4*)(g + (size_t)row * 64 + c);
        if (sc) {
            v.x = v.x * sc[c + 0] + sh[c + 0];
            v.y = v.y * sc[c + 1] + sh[c + 1];
            v.z = v.z * sc[c + 2] + sh[c + 2];
            v.w = v.w * sc[c + 3] + sh[c + 3];
        }
        *(float4*)(Ash + r * LDA + c) = v;
    }
}

__device__ __forceinline__ void stage_w(const float* __restrict__ g, int ldg,
                                        float* __restrict__ Wsh, int t)
{
#pragma unroll
    for (int i = 0; i < 4; ++i) {
        int idx = i * 256 + t;
        int k = idx >> 4;
        int f = (idx & 15) << 2;
        *(float4*)(Wsh + k * 64 + f) = *(const float4*)(g + (size_t)k * ldg + f);
    }
}

// 64x64 GEMM tile: 256 threads, each computes 4 nodes x 4 feats.
__device__ __forceinline__ void gemm_tile(const float* __restrict__ Ash, const float* __restrict__ Wsh,
                                          float acc[4][4], int n0, int f0)
{
#pragma unroll
    for (int k0 = 0; k0 < 64; k0 += 4) {
        float a[4][4], w[4][4];
#pragma unroll
        for (int i = 0; i < 4; ++i) {
            float4 t4 = *(const float4*)(Ash + (n0 + i) * LDA + k0);
            a[i][0] = t4.x; a[i][1] = t4.y; a[i][2] = t4.z; a[i][3] = t4.w;
        }
#pragma unroll
        for (int k = 0; k < 4; ++k) {
            float4 t4 = *(const float4*)(Wsh + (k0 + k) * 64 + f0);
            w[k][0] = t4.x; w[k][1] = t4.y; w[k][2] = t4.z; w[k][3] = t4.w;
        }
#pragma unroll
        for (int i = 0; i < 4; ++i)
#pragma unroll
            for (int k = 0; k < 4; ++k)
#pragma unroll
                for (int j = 0; j < 4; ++j)
                    acc[i][j] = fmaf(a[i][k], w[k][j], acc[i][j]);
    }
}

// ---------------------------------------------------------------- CSR build

__global__ void k_count(const int* __restrict__ dst, int* __restrict__ cnt, int E)
{
    int e = blockIdx.x * 256 + threadIdx.x;
    if (e < E) atomicAdd(&cnt[dst[e]], 1);
}

__global__ void k_scan(const int* __restrict__ cnt, int* __restrict__ rowptr, int n)
{
    __shared__ int part[1024];
    int t = threadIdx.x;
    int C = (n + 1023) >> 10;
    int lo = t * C, hi = min(lo + C, n);
    int s = 0;
    for (int i = lo; i < hi; ++i) s += cnt[i];
    part[t] = s;
    __syncthreads();
    for (int off = 1; off < 1024; off <<= 1) {
        int v = (t >= off) ? part[t - off] : 0;
        __syncthreads();
        part[t] += v;
        __syncthreads();
    }
    int pre = (t == 0) ? 0 : part[t - 1];
    for (int i = lo; i < hi; ++i) { rowptr[i] = pre; pre += cnt[i]; }
    if (t == 1023) rowptr[n] = part[1023];
}

__global__ void k_fill(const int* __restrict__ src, const int* __restrict__ dst,
                       const int* __restrict__ rowptr, int* __restrict__ cursor,
                       int* __restrict__ col, int E)
{
    int e = blockIdx.x * 256 + threadIdx.x;
    if (e < E) {
        int d = dst[e];
        int p = atomicAdd(&cursor[d], 1);
        col[rowptr[d] + p] = src[e];
    }
}

// ---------------------------------------------------------------- BN stats / finalize

__global__ void k_xstats(const float* __restrict__ x, float* __restrict__ stats, int N)
{
    __shared__ float rs[256], rq[256];
    int t = threadIdx.x;
    int f = t & 63, rg = t >> 6;
    float s = 0.f, q = 0.f;
    for (int r = blockIdx.x * 4 + rg; r < N; r += gridDim.x * 4) {
        float v = x[(size_t)r * 64 + f];
        s += v; q += v * v;
    }
    rs[rg * 64 + f] = s; rq[rg * 64 + f] = q;
    __syncthreads();
    if (t < 64) {
        float ts = rs[t] + rs[64 + t] + rs[128 + t] + rs[192 + t];
        float tq = rq[t] + rq[64 + t] + rq[128 + t] + rq[192 + t];
        atomicAdd(&stats[t], ts);
        atomicAdd(&stats[64 + t], tq);
    }
}

__global__ void k_finalize(const float* __restrict__ stats, const float* __restrict__ gamma,
                           const float* __restrict__ beta, float* __restrict__ ss, float invN)
{
    int t = threadIdx.x;
    if (t < 64) {
        float mu = stats[t] * invN;
        float var = stats[64 + t] * invN - mu * mu;
        float rs = rsqrtf(var + 1e-5f);
        float sc = gamma[t] * rs;
        ss[t] = sc;
        ss[64 + t] = beta[t] - mu * sc;
    }
}

// ---------------------------------------------------------------- input proj

__global__ void k_proj(const float* __restrict__ x, const float* __restrict__ ss,
                       const float* __restrict__ W, const float* __restrict__ b,
                       float* __restrict__ h, float* __restrict__ res, int N)
{
    __shared__ __align__(16) float Ash[64 * LDA];
    __shared__ __align__(16) float Wsh[64 * 64];
    int t = threadIdx.x;
    int base = blockIdx.x * 64;
    stage_tile(x, base, N, Ash, t, ss, ss + 64);
    stage_w(W, 64, Wsh, t);
    __syncthreads();
    int n0 = (t >> 4) << 2, f0 = (t & 15) << 2;
    float acc[4][4];
    float4 b4 = *(const float4*)(b + f0);
#pragma unroll
    for (int i = 0; i < 4; ++i) { acc[i][0] = b4.x; acc[i][1] = b4.y; acc[i][2] = b4.z; acc[i][3] = b4.w; }
    gemm_tile(Ash, Wsh, acc, n0, f0);
#pragma unroll
    for (int i = 0; i < 4; ++i) {
        int row = base + n0 + i;
        if (row < N) {
            float4 o = make_float4(fmaxf(acc[i][0], 0.f), fmaxf(acc[i][1], 0.f),
                                   fmaxf(acc[i][2], 0.f), fmaxf(acc[i][3], 0.f));
            *(float4*)(h + (size_t)row * 64 + f0) = o;
            *(float4*)(res + (size_t)row * 64 + f0) = o;
        }
    }
}

// ---------------------------------------------------------------- GIN aggregation (high-occupancy gather)
// one wave per node; lane = feature; unroll-8 edge batches for load concurrency

__global__ void __launch_bounds__(256, 8)
k_agg(const float* __restrict__ h, const int* __restrict__ rowptr,
      const int* __restrict__ col, float* __restrict__ agg, int N)
{
    int node = (blockIdx.x << 2) + (threadIdx.x >> 6);
    int lane = threadIdx.x & 63;
    if (node >= N) return;
    int e0 = rowptr[node], e1 = rowptr[node + 1];
    float a = h[(size_t)node * 64 + lane];  // (1+eps)*h_i with eps=0
    int e = e0;
    for (; e + 8 <= e1; e += 8) {
        int s0 = col[e + 0], s1 = col[e + 1], s2 = col[e + 2], s3 = col[e + 3];
        int s4 = col[e + 4], s5 = col[e + 5], s6 = col[e + 6], s7 = col[e + 7];
        float v0 = h[(size_t)s0 * 64 + lane];
        float v1 = h[(size_t)s1 * 64 + lane];
        float v2 = h[(size_t)s2 * 64 + lane];
        float v3 = h[(size_t)s3 * 64 + lane];
        float v4 = h[(size_t)s4 * 64 + lane];
        float v5 = h[(size_t)s5 * 64 + lane];
        float v6 = h[(size_t)s6 * 64 + lane];
        float v7 = h[(size_t)s7 * 64 + lane];
        a += ((v0 + v1) + (v2 + v3)) + ((v4 + v5) + (v6 + v7));
    }
    if (e + 4 <= e1) {
        int s0 = col[e + 0], s1 = col[e + 1], s2 = col[e + 2], s3 = col[e + 3];
        float v0 = h[(size_t)s0 * 64 + lane];
        float v1 = h[(size_t)s1 * 64 + lane];
        float v2 = h[(size_t)s2 * 64 + lane];
        float v3 = h[(size_t)s3 * 64 + lane];
        a += (v0 + v1) + (v2 + v3);
        e += 4;
    }
    if (e + 2 <= e1) {
        int s0 = col[e + 0], s1 = col[e + 1];
        float v0 = h[(size_t)s0 * 64 + lane];
        float v1 = h[(size_t)s1 * 64 + lane];
        a += v0 + v1;
        e += 2;
    }
    if (e < e1) a += h[(size_t)col[e] * 64 + lane];
    agg[(size_t)node * 64 + lane] = a;
}

// ---------------------------------------------------------------- 3-layer MLP + BN partial stats
// Reads agg (z buffer) in place: each block reads its 64 rows into LDS before writing them.

__global__ void k_mlp(const float* __restrict__ agg, const float* __restrict__ W3,
                      const float* __restrict__ b3, float* __restrict__ z,
                      float* __restrict__ stats, int N)
{
    __shared__ __align__(16) float Ash[64 * LDA];
    __shared__ __align__(16) float Bsh[64 * LDA];
    __shared__ __align__(16) float Wsh[64 * 64];
    int t = threadIdx.x;
    int base = blockIdx.x * 64;

    stage_tile(agg, base, N, Ash, t, nullptr, nullptr);
    stage_w(W3, 64, Wsh, t);
    __syncthreads();

    int n0 = (t >> 4) << 2, f0 = (t & 15) << 2;
    float acc[4][4];

    // linear 1 + relu
    {
        float4 b4 = *(const float4*)(b3 + f0);
#pragma unroll
        for (int i = 0; i < 4; ++i) { acc[i][0] = b4.x; acc[i][1] = b4.y; acc[i][2] = b4.z; acc[i][3] = b4.w; }
    }
    gemm_tile(Ash, Wsh, acc, n0, f0);
    __syncthreads();
#pragma unroll
    for (int i = 0; i < 4; ++i) {
        float4 o = make_float4(fmaxf(acc[i][0], 0.f), fmaxf(acc[i][1], 0.f),
                               fmaxf(acc[i][2], 0.f), fmaxf(acc[i][3], 0.f));
        *(float4*)(Bsh + (n0 + i) * LDA + f0) = o;
    }
    stage_w(W3 + 64 * 64, 64, Wsh, t);
    __syncthreads();

    // linear 2 + relu
    {
        float4 b4 = *(const float4*)(b3 + 64 + f0);
#pragma unroll
        for (int i = 0; i < 4; ++i) { acc[i][0] = b4.x; acc[i][1] = b4.y; acc[i][2] = b4.z; acc[i][3] = b4.w; }
    }
    gemm_tile(Bsh, Wsh, acc, n0, f0);
    __syncthreads();
#pragma unroll
    for (int i = 0; i < 4; ++i) {
        float4 o = make_float4(fmaxf(acc[i][0], 0.f), fmaxf(acc[i][1], 0.f),
                               fmaxf(acc[i][2], 0.f), fmaxf(acc[i][3], 0.f));
        *(float4*)(Ash + (n0 + i) * LDA + f0) = o;
    }
    stage_w(W3 + 2 * 64 * 64, 64, Wsh, t);
    __syncthreads();

    // linear 3 (no relu; BN follows)
    {
        float4 b4 = *(const float4*)(b3 + 128 + f0);
#pragma unroll
        for (int i = 0; i < 4; ++i) { acc[i][0] = b4.x; acc[i][1] = b4.y; acc[i][2] = b4.z; acc[i][3] = b4.w; }
    }
    gemm_tile(Ash, Wsh, acc, n0, f0);

    // write z + per-block BN partial stats
    float s[4] = {0.f, 0.f, 0.f, 0.f}, q[4] = {0.f, 0.f, 0.f, 0.f};
#pragma unroll
    for (int i = 0; i < 4; ++i) {
        int row = base + n0 + i;
        if (row < N) {
            *(float4*)(z + (size_t)row * 64 + f0) =
                make_float4(acc[i][0], acc[i][1], acc[i][2], acc[i][3]);
#pragma unroll
            for (int j = 0; j < 4; ++j) { s[j] += acc[i][j]; q[j] += acc[i][j] * acc[i][j]; }
        }
    }
    int ng = t >> 4;
#pragma unroll
    for (int j = 0; j < 4; ++j) {
        Bsh[ng * 64 + f0 + j] = s[j];
        Bsh[1024 + ng * 64 + f0 + j] = q[j];
    }
    __syncthreads();
    if (t < 64) {
        float ts = 0.f, tq = 0.f;
#pragma unroll
        for (int g2 = 0; g2 < 16; ++g2) { ts += Bsh[g2 * 64 + t]; tq += Bsh[1024 + g2 * 64 + t]; }
        atomicAdd(&stats[t], ts);
        atomicAdd(&stats[64 + t], tq);
    }
}

// ---------------------------------------------------------------- BN apply + relu (+ residual)

__global__ void k_bnrelu(const float4* __restrict__ z4, const float* __restrict__ ss,
                         float4* __restrict__ h4, float4* __restrict__ res4,
                         int second, int total4)
{
    int idx = blockIdx.x * 256 + threadIdx.x;
    if (idx >= total4) return;
    int c = (idx & 15) << 2;
    float4 v = z4[idx];
    v.x = fmaxf(v.x * ss[c + 0] + ss[64 + c + 0], 0.f);
    v.y = fmaxf(v.y * ss[c + 1] + ss[64 + c + 1], 0.f);
    v.z = fmaxf(v.z * ss[c + 2] + ss[64 + c + 2], 0.f);
    v.w = fmaxf(v.w * ss[c + 3] + ss[64 + c + 3], 0.f);
    if (second) {
        float4 r = res4[idx];
        v.x += r.x; v.y += r.y; v.z += r.z; v.w += r.w;
        res4[idx] = v;
    }
    h4[idx] = v;
}

// ---------------------------------------------------------------- attention readout

__global__ void k_wks(const float* __restrict__ Wk, const float* __restrict__ seed,
                      float* __restrict__ wks)
{
    int t = threadIdx.x;  // 256
    int i = t >> 2, hh = t & 3;
    float s = 0.f;
#pragma unroll
    for (int d = 0; d < 16; ++d) s += Wk[i * 64 + hh * 16 + d] * seed[hh * 16 + d];
    wks[i * 4 + hh] = s * 0.25f;  // 1/sqrt(16)
}

__global__ void k_vs(const float* __restrict__ h, const float* __restrict__ Wv,
                     const float* __restrict__ wksg, float* __restrict__ v,
                     float* __restrict__ scores, int N)
{
    __shared__ __align__(16) float Ash[64 * LDA];
    __shared__ __align__(16) float Wsh[64 * 64];
    __shared__ float wk[256];
    int t = threadIdx.x;
    int base = blockIdx.x * 64;
    stage_tile(h, base, N, Ash, t, nullptr, nullptr);
    stage_w(Wv, 64, Wsh, t);
    wk[t] = wksg[t];
    __syncthreads();
    int n0 = (t >> 4) << 2, f0 = (t & 15) << 2;
    float acc[4][4] = {};
    gemm_tile(Ash, Wsh, acc, n0, f0);
#pragma unroll
    for (int i = 0; i < 4; ++i) {
        int row = base + n0 + i;
        if (row < N)
            *(float4*)(v + (size_t)row * 64 + f0) =
                make_float4(acc[i][0], acc[i][1], acc[i][2], acc[i][3]);
    }
    // scores = h @ wk_s  (one thread per (node, head))
    int n = t >> 2, hh = t & 3;
    float s = 0.f;
#pragma unroll
    for (int k0 = 0; k0 < 64; k0 += 4) {
        float4 a = *(const float4*)(Ash + n * LDA + k0);
        s += a.x * wk[(k0 + 0) * 4 + hh];
        s += a.y * wk[(k0 + 1) * 4 + hh];
        s += a.z * wk[(k0 + 2) * 4 + hh];
        s += a.w * wk[(k0 + 3) * 4 + hh];
    }
    int row = base + n;
    if (row < N) scores[(size_t)row * 4 + hh] = s;
}

__global__ void k_bounds(const int* __restrict__ batch, int* __restrict__ gs,
                         int* __restrict__ ge, int N)
{
    int i = blockIdx.x * 256 + threadIdx.x;
    if (i < N) {
        int b = batch[i];
        atomicMin(&gs[b], i);
        atomicMax(&ge[b], i + 1);
    }
}

__global__ void k_pool(const float4* __restrict__ scores4, const float* __restrict__ v,
                       const int* __restrict__ gs, const int* __restrict__ ge,
                       float* __restrict__ pooled, int N)
{
    int g = blockIdx.x;
    int s = gs[g], e = ge[g];
    int t = threadIdx.x;
    __shared__ float4 rmax[256];
    __shared__ float racc[256];
    __shared__ float resum[16];
    if (s >= e) {
        if (t < 64) pooled[g * 64 + t] = 0.f;
        return;
    }
    // phase 1: per-head max
    float4 m = make_float4(-1e30f, -1e30f, -1e30f, -1e30f);
    for (int i = s + t; i < e; i += 256) {
        float4 sc = scores4[i];
        m.x = fmaxf(m.x, sc.x); m.y = fmaxf(m.y, sc.y);
        m.z = fmaxf(m.z, sc.z); m.w = fmaxf(m.w, sc.w);
    }
    rmax[t] = m;
    __syncthreads();
    for (int off = 128; off; off >>= 1) {
        if (t < off) {
            float4 a = rmax[t], b = rmax[t + off];
            a.x = fmaxf(a.x, b.x); a.y = fmaxf(a.y, b.y);
            a.z = fmaxf(a.z, b.z); a.w = fmaxf(a.w, b.w);
            rmax[t] = a;
        }
        __syncthreads();
    }
    float4 smax = rmax[0];
    int rg = t >> 6, f = t & 63, hh = f >> 4;
    float mx = (hh == 0) ? smax.x : ((hh == 1) ? smax.y : ((hh == 2) ? smax.z : smax.w));
    // phase 2: sum e and e*v
    float acc = 0.f, es = 0.f;
    for (int i = s + rg; i < e; i += 4) {
        float4 sc = scores4[i];
        float scl = (hh == 0) ? sc.x : ((hh == 1) ? sc.y : ((hh == 2) ? sc.z : sc.w));
        float ev = __expf(scl - mx);
        acc += ev * v[(size_t)i * 64 + f];
        if ((f & 15) == 0) es += ev;
    }
    racc[rg * 64 + f] = acc;
    if ((f & 15) == 0) resum[rg * 4 + hh] = es;
    __syncthreads();
    if (t < 64) {
        float tot = racc[t] + racc[64 + t] + racc[128 + t] + racc[192 + t];
        int h2 = t >> 4;
        float den = resum[h2] + resum[4 + h2] + resum[8 + h2] + resum[12 + h2];
        pooled[g * 64 + t] = tot / den;
    }
}

__global__ void k_embed(const float* __restrict__ pooled, const float* __restrict__ Wo,
                        float* __restrict__ out, int G)
{
    __shared__ __align__(16) float Ash[64 * LDA];
    __shared__ __align__(16) float Wsh[64 * 64];
    int t = threadIdx.x;
    int base = blockIdx.x * 64;
    stage_tile(pooled, base, G, Ash, t, nullptr, nullptr);
    stage_w(Wo, 64, Wsh, t);
    __syncthreads();
    int n0 = (t >> 4) << 2, f0 = (t & 15) << 2;
    float acc[4][4] = {};
    gemm_tile(Ash, Wsh, acc, n0, f0);
#pragma unroll
    for (int i = 0; i < 4; ++i) {
        int row = base + n0 + i;
        if (row < G)
            *(float4*)(out + (size_t)row * 64 + f0) =
                make_float4(acc[i][0], acc[i][1], acc[i][2], acc[i][3]);
    }
}

__global__ void k_logits(const float* __restrict__ embed, const float* __restrict__ W,
                         const float* __restrict__ b, float* __restrict__ out, int G)
{
    __shared__ __align__(16) float Ash[64 * LDA];
    __shared__ __align__(16) float Wsh[64 * 64];
    int t = threadIdx.x;
    int base = blockIdx.x * 64;
    int co = blockIdx.y * 64;
    stage_tile(embed, base, G, Ash, t, nullptr, nullptr);
    // stage 64x64 slice of [64,128] pred_W
#pragma unroll
    for (int i = 0; i < 4; ++i) {
        int idx = i * 256 + t;
        int k = idx >> 4;
        int f = (idx & 15) << 2;
        *(float4*)(Wsh + k * 64 + f) = *(const float4*)(W + (size_t)k * 128 + co + f);
    }
    __syncthreads();
    int n0 = (t >> 4) << 2, f0 = (t & 15) << 2;
    float acc[4][4];
    float4 b4 = *(const float4*)(b + co + f0);
#pragma unroll
    for (int i = 0; i < 4; ++i) { acc[i][0] = b4.x; acc[i][1] = b4.y; acc[i][2] = b4.z; acc[i][3] = b4.w; }
    gemm_tile(Ash, Wsh, acc, n0, f0);
#pragma unroll
    for (int i = 0; i < 4; ++i) {
        int row = base + n0 + i;
        if (row < G)
            *(float4*)(out + (size_t)row * 128 + co + f0) =
                make_float4(acc[i][0], acc[i][1], acc[i][2], acc[i][3]);
    }
}

// ---------------------------------------------------------------- launch

extern "C" void kernel_launch(void* const* d_in, const int* in_sizes, int n_in,
                              void* d_out, int out_size, void* d_ws, size_t ws_size,
                              hipStream_t stream)
{
    const float* x     = (const float*)d_in[0];
    const int*   eidx  = (const int*)d_in[1];
    const int*   batch = (const int*)d_in[2];
    const float* fn_g  = (const float*)d_in[3];
    const float* fn_b  = (const float*)d_in[4];
    const float* pW    = (const float*)d_in[5];
    const float* pb    = (const float*)d_in[6];
    const float* mlpW  = (const float*)d_in[7];
    const float* mlpb  = (const float*)d_in[8];
    const float* ngm   = (const float*)d_in[9];
    const float* nbt   = (const float*)d_in[10];
    const float* seed  = (const float*)d_in[11];
    const float* Wk    = (const float*)d_in[12];
    const float* Wv    = (const float*)d_in[13];
    const float* Wo    = (const float*)d_in[14];
    const float* predW = (const float*)d_in[15];
    const float* predb = (const float*)d_in[16];

    const int N = 100000, E = 1000000, G = 1000;
    const int* srcv = eidx;
    const int* dstv = eidx + E;

    char* w = (char*)d_ws;
    auto alloc = [&](size_t bytes) {
        char* p = w;
        w += (bytes + 255) & ~(size_t)255;
        return p;
    };
    const size_t NPAD = 100032;  // 1563 * 64
    float* h      = (float*)alloc(NPAD * 64 * 4);
    float* res    = (float*)alloc(NPAD * 64 * 4);
    float* z      = (float*)alloc(NPAD * 64 * 4);   // agg in, MLP out (in-place), also reused as v
    int*   rowptr = (int*)alloc((size_t)(N + 1) * 4);
    int*   cnt    = (int*)alloc((size_t)N * 4);
    int*   col    = (int*)alloc((size_t)E * 4);
    float* stats  = (float*)alloc(9 * 128 * 4);
    float* ss     = (float*)alloc(9 * 128 * 4);
    float* wks    = (float*)alloc(256 * 4);
    float* scores = (float*)alloc(NPAD * 4 * 4);
    int*   gs     = (int*)alloc((size_t)G * 4);
    int*   ge     = (int*)alloc((size_t)G * 4);
    float* pooled = (float*)alloc((size_t)G * 64 * 4);

    float* emb    = (float*)d_out;            // [G,64]
    float* logits = (float*)d_out + G * 64;   // [G,128]

    const int NB = (N + 63) / 64;  // 1563
    const float invN = 1.f / (float)N;

    // CSR build
    hipMemsetAsync(cnt, 0, (size_t)N * 4, stream);
    hipMemsetAsync(stats, 0, 9 * 128 * 4, stream);
    k_count<<<(E + 255) / 256, 256, 0, stream>>>(dstv, cnt, E);
    k_scan<<<1, 1024, 0, stream>>>(cnt, rowptr, N);
    hipMemsetAsync(cnt, 0, (size_t)N * 4, stream);
    k_fill<<<(E + 255) / 256, 256, 0, stream>>>(srcv, dstv, rowptr, cnt, col, E);

    // feature BN + projection
    k_xstats<<<512, 256, 0, stream>>>(x, stats, N);
    k_finalize<<<1, 64, 0, stream>>>(stats, fn_g, fn_b, ss, invN);
    k_proj<<<NB, 256, 0, stream>>>(x, ss, pW, pb, h, res, N);

    // 4 MPNN blocks x 2 GIN convs
    for (int m = 0; m < 4; ++m)
        for (int c = 0; c < 2; ++c) {
            int sidx = 1 + m * 2 + c;
            k_agg<<<(N + 3) / 4, 256, 0, stream>>>(h, rowptr, col, z, N);
            k_mlp<<<NB, 256, 0, stream>>>(z,
                                          mlpW + (size_t)m * 3 * 64 * 64,
                                          mlpb + (size_t)m * 3 * 64,
                                          z, stats + sidx * 128, N);
            k_finalize<<<1, 64, 0, stream>>>(stats + sidx * 128, ngm + m * 64, nbt + m * 64,
                                             ss + sidx * 128, invN);
            k_bnrelu<<<(N * 16 + 255) / 256, 256, 0, stream>>>(
                (const float4*)z, ss + sidx * 128, (float4*)h, (float4*)res, (c == 1) ? 1 : 0, N * 16);
        }

    // attention readout
    k_wks<<<1, 256, 0, stream>>>(Wk, seed, wks);
    k_vs<<<NB, 256, 0, stream>>>(h, Wv, wks, z, scores, N);
    hipMemsetAsync(gs, 0x7f, (size_t)G * 4, stream);
    hipMemsetAsync(ge, 0, (size_t)G * 4, stream);
    k_bounds<<<(N + 255) / 256, 256, 0, stream>>>(batch, gs, ge, N);
    k_pool<<<G, 256, 0, stream>>>((const float4*)scores, z, gs, ge, pooled, N);
    k_embed<<<(G + 63) / 64, 256, 0, stream>>>(pooled, Wo, emb, G);
    dim3 lg((G + 63) / 64, 2);
    k_logits<<<lg, 256, 0, stream>>>(emb, predW, predb, logits, G);
}